// Round 7
// baseline (427.802 us; speedup 1.0000x reference)
//
#include <hip/hip_runtime.h>
#include <stdint.h>

#define NB   8
#define TOK  4096
#define DIM  512
#define HALF 2048
#define RR   1024
#define NT   24      // K-tiles of 64 (3 thirds x 512/64)

typedef unsigned long long u64;
typedef unsigned int u32;
typedef _Float16 f16;
typedef f16 f16x4 __attribute__((ext_vector_type(4)));
typedef f16 f16x8 __attribute__((ext_vector_type(8)));
typedef float f32x4 __attribute__((ext_vector_type(4)));

#define AS1 __attribute__((address_space(1)))
#define AS3 __attribute__((address_space(3)))
#define GLL16(GP, LP) __builtin_amdgcn_global_load_lds((const AS1 u32*)(GP), (AS3 u32*)(LP), 16, 0, 0)
#define SBAR() __builtin_amdgcn_s_barrier()
#define VMCNT0() asm volatile("s_waitcnt vmcnt(0)" ::: "memory")

__device__ __forceinline__ u32 mono_f32(float f) {
    u32 u = __float_as_uint(f);
    return (u & 0x80000000u) ? ~u : (u | 0x80000000u);
}
__device__ __forceinline__ u64 umax64(u64 a, u64 b) { return a > b ? a : b; }

// ---------------- K0: init ----------------
__global__ void k_init(u64* __restrict__ best, u64* __restrict__ wkey) {
    int i = blockIdx.x * 256 + threadIdx.x;
    if (i < NB * HALF) { best[i] = 0ull; wkey[i] = ~0ull; }
}

// ---------------- fused split + norms ----------------
__global__ void k_prep(const float* __restrict__ x, f16* __restrict__ xh, f16* __restrict__ xl,
                       float* __restrict__ invn) {
    int row  = blockIdx.x * 4 + (threadIdx.x >> 6);
    int lane = threadIdx.x & 63;
    const float* p = x + (size_t)row * DIM + 4 * lane;
    float4 v0 = *(const float4*)p;
    float4 v1 = *(const float4*)(p + 256);
    float va[8] = {v0.x, v0.y, v0.z, v0.w, v1.x, v1.y, v1.z, v1.w};
    f16x4 h0, h1, l0, l1;
#pragma unroll
    for (int e = 0; e < 4; ++e) {
        f16 hh = (f16)va[e];     h0[e] = hh;  l0[e] = (f16)(va[e] - (float)hh);
        f16 hh1 = (f16)va[e+4];  h1[e] = hh1; l1[e] = (f16)(va[e+4] - (float)hh1);
    }
    size_t off = (size_t)row * DIM + 4 * lane;
    *(f16x4*)(xh + off)       = h0;
    *(f16x4*)(xh + off + 256) = h1;
    *(f16x4*)(xl + off)       = l0;
    *(f16x4*)(xl + off + 256) = l1;
    float ss = va[0]*va[0] + va[1]*va[1] + va[2]*va[2] + va[3]*va[3]
             + va[4]*va[4] + va[5]*va[5] + va[6]*va[6] + va[7]*va[7];
#pragma unroll
    for (int m = 32; m; m >>= 1) ss += __shfl_xor(ss, m, 64);
    if (lane == 0) invn[row] = 1.0f / fmaxf(sqrtf(ss), 1e-12f);
}

// ---------------- split + transpose W ----------------
__global__ void k_wsplit(const float* __restrict__ W, f16* __restrict__ Wh, f16* __restrict__ Wl) {
    __shared__ float tile[64][65];
    int k0 = (blockIdx.x >> 3) * 64, n0 = (blockIdx.x & 7) * 64;
    int t = threadIdx.x;
#pragma unroll
    for (int i = 0; i < 16; ++i) {
        int idx = t + 256 * i;
        int r = idx >> 6, c = idx & 63;
        tile[r][c] = W[(size_t)(k0 + r) * DIM + n0 + c];
    }
    __syncthreads();
#pragma unroll
    for (int i = 0; i < 16; ++i) {
        int idx = t + 256 * i;
        int n = idx >> 6, k = idx & 63;
        float v = tile[k][n];
        f16 h = (f16)v;
        Wh[(size_t)(n0 + n) * DIM + k0 + k] = h;
        Wl[(size_t)(n0 + n) * DIM + k0 + k] = (f16)(v - (float)h);
    }
}

// ======== shared 256x256 pipelined GEMM core (macros) ========
// A: LDS dbuf [2][2 half][128][64] f16 (64 KB), XOR-swizzled (chunk^ (row&7)), GLL16-staged.
// B: per-wave registers, global->reg, dbuf via tile-parity.
// 4 phases/K-tile: q0 {A-frags i0,1 | B(t+1) reg loads}, q1 {i2,3 | GLL A-h0(t+1)},
// q2 {i4,5 | GLL A-h1(t+1)}, q3 {i6,7 | vmcnt(0)}. Each phase: barrier; MFMA x16; barrier.

#define PHASE_MFMA(I0, A00, A01, A10, A11, BC) \
  __builtin_amdgcn_s_setprio(1); \
  _Pragma("unroll") \
  for (int j_ = 0; j_ < 4; ++j_) { \
    acc[I0][j_]     = __builtin_amdgcn_mfma_f32_16x16x32_f16(A00, BC[j_*2],   acc[I0][j_],     0,0,0); \
    acc[I0][j_]     = __builtin_amdgcn_mfma_f32_16x16x32_f16(A01, BC[j_*2+1], acc[I0][j_],     0,0,0); \
    acc[(I0)+1][j_] = __builtin_amdgcn_mfma_f32_16x16x32_f16(A10, BC[j_*2],   acc[(I0)+1][j_], 0,0,0); \
    acc[(I0)+1][j_] = __builtin_amdgcn_mfma_f32_16x16x32_f16(A11, BC[j_*2+1], acc[(I0)+1][j_], 0,0,0); \
  } \
  __builtin_amdgcn_s_setprio(0);

#define PHASE(Q, BCARR, STAGE) { \
  const f16* Ap_ = Ab_ + (2*(Q))*1024 + rm*64; \
  f16x8 a00_ = *(const f16x8*)(Ap_ + ex0); \
  f16x8 a01_ = *(const f16x8*)(Ap_ + ex1); \
  f16x8 a10_ = *(const f16x8*)(Ap_ + 1024 + ex0); \
  f16x8 a11_ = *(const f16x8*)(Ap_ + 1024 + ex1); \
  STAGE \
  SBAR(); \
  PHASE_MFMA(2*(Q), a00_, a01_, a10_, a11_, BCARR) \
  SBAR(); \
}

#define TILE(T, CUR, BC, BNX, AH, AL, BH, BL) { \
  const f16* Ab_ = A0 + (CUR)*16384 + wr*8192; \
  f16* Ad_ = A0 + (1-(CUR))*16384; \
  const int tn_ = (T) + 1; \
  const int ok_ = tn_ < NT; \
  const int thn_ = tn_ >> 3; \
  const int coln_ = (tn_ & 7) << 6; \
  const f16* An_ = (thn_ == 1) ? (AL) : (AH); \
  const f16* Bn_ = (thn_ == 2) ? (BL) : (BH); \
  PHASE(0, BC, { if (ok_) { _Pragma("unroll") for (int j_ = 0; j_ < 4; ++j_) { \
      BNX[j_*2]   = *(const f16x8*)(Bn_ + boff[j_] + coln_); \
      BNX[j_*2+1] = *(const f16x8*)(Bn_ + boff[j_] + coln_ + 32); } } }) \
  PHASE(1, BC, { if (ok_) { \
      GLL16(An_ + aoff[0][0] + coln_, Ad_ + (size_t)(w*64)*8); \
      GLL16(An_ + aoff[1][0] + coln_, Ad_ + (size_t)(512 + w*64)*8); } }) \
  PHASE(2, BC, { if (ok_) { \
      GLL16(An_ + aoff[0][1] + coln_, Ad_ + (size_t)(1024 + w*64)*8); \
      GLL16(An_ + aoff[1][1] + coln_, Ad_ + (size_t)(1536 + w*64)*8); } }) \
  PHASE(3, BC, { VMCNT0(); }) \
}

// ---------------- scores GEMM: fused argmax ----------------
__launch_bounds__(512, 2)
__global__ void k_scores(const f16* __restrict__ xh, const f16* __restrict__ xl,
                         const float* __restrict__ invn, u64* __restrict__ best) {
    __shared__ __align__(16) f16 Alds[2][2][128][64];   // 64 KB
    int bx = blockIdx.x;
    int b = bx >> 6, sb = (bx >> 3) & 7, tb = bx & 7;
    int tid = threadIdx.x, lane = tid & 63, w = tid >> 6;
    int wr = w >> 2, wc = w & 3;
    int cc = lane >> 4, rm = lane & 15, rm7 = rm & 7;
    f16* A0 = &Alds[0][0][0][0];

    int slot = tid & 7, mrow = tid >> 3;
    int chunk = slot ^ (mrow & 7);
    size_t aoff[2][2];
#pragma unroll
    for (int r = 0; r < 2; ++r)
#pragma unroll
        for (int h = 0; h < 2; ++h) {
            int m = r * 64 + mrow;
            aoff[r][h] = ((size_t)b * TOK + 2 * (sb * 256 + h * 128 + m) + 1) * DIM + chunk * 8;
        }
    size_t boff[4];
#pragma unroll
    for (int j = 0; j < 4; ++j)
        boff[j] = ((size_t)b * TOK + 2 * (tb * 256 + wc * 64 + j * 16 + rm)) * DIM + cc * 8;
    int ex0 = 8 * (cc ^ rm7), ex1 = ex0 ^ 32;

    f32x4 acc[8][4];
#pragma unroll
    for (int i = 0; i < 8; ++i)
#pragma unroll
        for (int j = 0; j < 4; ++j) acc[i][j] = (f32x4){0.f, 0.f, 0.f, 0.f};

    f16x8 b0[8], b1[8];
    // prologue: stage A(0), load B(0) (tile 0 = third 0 -> xh/xh)
#pragma unroll
    for (int h = 0; h < 2; ++h)
#pragma unroll
        for (int r = 0; r < 2; ++r)
            GLL16(xh + aoff[r][h], A0 + (size_t)(h * 1024 + r * 512 + w * 64) * 8);
#pragma unroll
    for (int j = 0; j < 4; ++j) {
        b0[j*2]   = *(const f16x8*)(xh + boff[j]);
        b0[j*2+1] = *(const f16x8*)(xh + boff[j] + 32);
    }
    VMCNT0();
    SBAR();

#pragma unroll 1
    for (int tp = 0; tp < 12; ++tp) {
        TILE(2*tp,   0, b0, b1, xh, xl, xh, xl)
        TILE(2*tp+1, 1, b1, b0, xh, xl, xh, xl)
    }

    // epilogue: normalize, row argmax, atomicMax
    float invd[4];
#pragma unroll
    for (int j = 0; j < 4; ++j) {
        int t = tb * 256 + wc * 64 + j * 16 + rm;
        invd[j] = invn[(size_t)b * TOK + 2 * t];
    }
#pragma unroll
    for (int i = 0; i < 8; ++i) {
#pragma unroll
        for (int r = 0; r < 4; ++r) {
            int s = sb * 256 + wr * 128 + i * 16 + cc * 4 + r;
            float invs = invn[(size_t)b * TOK + 2 * s + 1];
            u64 key = 0;
#pragma unroll
            for (int j = 0; j < 4; ++j) {
                int t = tb * 256 + wc * 64 + j * 16 + rm;
                float sc = acc[i][j][r] * invs * invd[j];
                u64 k = ((u64)mono_f32(sc) << 32) | (u32)(2047 - t);
                key = umax64(key, k);
            }
#pragma unroll
            for (int m = 1; m < 16; m <<= 1) {
                u32 lo = (u32)key, hi = (u32)(key >> 32);
                lo = __shfl_xor(lo, m, 64);
                hi = __shfl_xor(hi, m, 64);
                key = umax64(key, ((u64)hi << 32) | lo);
            }
            if (rm == 0) atomicMax(&best[b * HALF + s], key);
        }
    }
}

// ---------------- top-k + duplicate-dst winner ----------------
__global__ void k_topk(const u64* __restrict__ best, u64* __restrict__ wkey,
                       u32* __restrict__ member, u32* __restrict__ dstmap) {
    __shared__ u32 smono[HALF];
    int b = blockIdx.x >> 4, sc = blockIdx.x & 15;
    int tid = threadIdx.x;
#pragma unroll
    for (int r = 0; r < 8; ++r) { int s = r * 256 + tid; smono[s] = (u32)(best[b * HALF + s] >> 32); }
    __syncthreads();
    int s = sc * 128 + (tid >> 1);
    u32 ms = smono[s];
    int t0 = (tid & 1) * 1024;
    int cnt = 0;
    for (int t = t0; t < t0 + 1024; ++t) {
        u32 mt = smono[t];
        cnt += ((mt > ms) || (mt == ms && t < s)) ? 1 : 0;
    }
    int oth = __shfl_xor(cnt, 1, 64);
    if ((tid & 1) == 0) {
        int rank = cnt + oth;
        u64 k = best[b * HALF + s];
        u32 d = 2047u - (u32)(k & 0xffffffffu);
        dstmap[b * HALF + s] = d;
        u32 mem = (rank < RR) ? 1u : 0u;
        member[b * HALF + s] = mem;
        if (mem) {
            u64 key = (k & 0xffffffff00000000ull) | (u32)(2047 - s);
            atomicMin(&wkey[b * HALF + d], key);
        }
    }
}

// ---------------- merged dst rows -> split((dst+src)/2) ----------------
__global__ void k_merge2(const float* __restrict__ x, const u64* __restrict__ wkey,
                         f16* __restrict__ xh, f16* __restrict__ xl) {
    int idx = blockIdx.x;
    int b = idx >> 11, d = idx & (HALF - 1);
    u64 wk = wkey[b * HALF + d];
    if (wk == ~0ull) return;
    int s = 2047 - (int)(wk & 0xffffffffu);
    const float* xd = x + ((size_t)b * TOK + 2 * d) * DIM;
    const float* xs = x + ((size_t)b * TOK + 2 * s + 1) * DIM;
    int l0 = threadIdx.x * 8;
    f16x8 h, l;
#pragma unroll
    for (int e = 0; e < 8; ++e) {
        float v = (xd[l0 + e] + xs[l0 + e]) * 0.5f;
        f16 hh = (f16)v;
        h[e] = hh;
        l[e] = (f16)(v - (float)hh);
    }
    size_t off = ((size_t)b * TOK + 2 * d) * DIM + l0;
    *(f16x8*)(xh + off) = h;
    *(f16x8*)(xl + off) = l;
}

// ---------------- y = x_merged @ W + b ----------------
__launch_bounds__(512, 2)
__global__ void k_out(const f16* __restrict__ xh, const f16* __restrict__ xl,
                      const f16* __restrict__ Wh, const f16* __restrict__ Wl,
                      const float* __restrict__ bias, float* __restrict__ out) {
    __shared__ __align__(16) f16 Alds[2][2][128][64];
    int bx = blockIdx.x;
    int im = bx >> 1, in = bx & 1;
    int tid = threadIdx.x, lane = tid & 63, w = tid >> 6;
    int wr = w >> 2, wc = w & 3;
    int cc = lane >> 4, rm = lane & 15, rm7 = rm & 7;
    f16* A0 = &Alds[0][0][0][0];

    int slot = tid & 7, mrow = tid >> 3;
    int chunk = slot ^ (mrow & 7);
    size_t aoff[2][2];
#pragma unroll
    for (int r = 0; r < 2; ++r)
#pragma unroll
        for (int h = 0; h < 2; ++h)
            aoff[r][h] = (size_t)(im * 256 + h * 128 + r * 64 + mrow) * DIM + chunk * 8;
    size_t boff[4];
#pragma unroll
    for (int j = 0; j < 4; ++j)
        boff[j] = (size_t)(in * 256 + wc * 64 + j * 16 + rm) * DIM + cc * 8;
    int ex0 = 8 * (cc ^ rm7), ex1 = ex0 ^ 32;

    f32x4 acc[8][4];
#pragma unroll
    for (int i = 0; i < 8; ++i)
#pragma unroll
        for (int j = 0; j < 4; ++j) acc[i][j] = (f32x4){0.f, 0.f, 0.f, 0.f};

    f16x8 b0[8], b1[8];
#pragma unroll
    for (int h = 0; h < 2; ++h)
#pragma unroll
        for (int r = 0; r < 2; ++r)
            GLL16(xh + aoff[r][h], A0 + (size_t)(h * 1024 + r * 512 + w * 64) * 8);
#pragma unroll
    for (int j = 0; j < 4; ++j) {
        b0[j*2]   = *(const f16x8*)(Wh + boff[j]);
        b0[j*2+1] = *(const f16x8*)(Wh + boff[j] + 32);
    }
    VMCNT0();
    SBAR();

#pragma unroll 1
    for (int tp = 0; tp < 12; ++tp) {
        TILE(2*tp,   0, b0, b1, xh, xl, Wh, Wl)
        TILE(2*tp+1, 1, b1, b0, xh, xl, Wh, Wl)
    }

    float bj[4];
#pragma unroll
    for (int j = 0; j < 4; ++j) bj[j] = bias[in * 256 + wc * 64 + j * 16 + rm];
#pragma unroll
    for (int i = 0; i < 8; ++i) {
#pragma unroll
        for (int r = 0; r < 4; ++r) {
            int gm = im * 256 + wr * 128 + i * 16 + cc * 4 + r;
#pragma unroll
            for (int j = 0; j < 4; ++j) {
                int n = in * 256 + wc * 64 + j * 16 + rm;
                out[(size_t)gm * DIM + n] = acc[i][j][r] + bj[j];
            }
        }
    }
}

// ---------------- merged src rows copy dst hidden row ----------------
__global__ void k_fix(const u32* __restrict__ member, const u32* __restrict__ dstmap,
                      float* __restrict__ out) {
    int idx = blockIdx.x;
    if (!member[idx]) return;
    int b = idx >> 11, s = idx & (HALF - 1);
    const float* sp = out + ((size_t)b * TOK + 2 * (size_t)dstmap[idx]) * DIM;
    float*       dp = out + ((size_t)b * TOK + 2 * (size_t)s + 1) * DIM;
    int l = threadIdx.x;
    *(float4*)(dp + 4 * l) = *(const float4*)(sp + 4 * l);
}

extern "C" void kernel_launch(void* const* d_in, const int* in_sizes, int n_in,
                              void* d_out, int out_size, void* d_ws, size_t ws_size,
                              hipStream_t stream) {
    const float* x    = (const float*)d_in[0];
    const float* W    = (const float*)d_in[1];
    const float* bias = (const float*)d_in[2];
    float* out = (float*)d_out;

    char* ws = (char*)d_ws;
    f16*   xh     = (f16*)(ws);                               // 32 MB
    f16*   xl     = (f16*)(ws + (32u << 20));                 // 32 MB
    f16*   Wh     = (f16*)(ws + (64u << 20));                 // 512 KB
    f16*   Wl     = (f16*)(ws + (64u << 20) + (512u << 10));  // 512 KB
    float* invn   = (float*)(ws + (65u << 20));               // 128 KB
    u64*   best   = (u64*)(ws + (65u << 20) + (128u << 10));  // 128 KB
    u64*   wkey   = (u64*)(ws + (65u << 20) + (256u << 10));  // 128 KB
    u32*   dstmap = (u32*)(ws + (65u << 20) + (384u << 10));  //  64 KB
    u32*   member = (u32*)(ws + (65u << 20) + (448u << 10));  //  64 KB

    hipLaunchKernelGGL(k_init,   dim3(64),    dim3(256), 0, stream, best, wkey);
    hipLaunchKernelGGL(k_prep,   dim3(8192),  dim3(256), 0, stream, x, xh, xl, invn);
    hipLaunchKernelGGL(k_wsplit, dim3(64),    dim3(256), 0, stream, W, Wh, Wl);
    hipLaunchKernelGGL(k_scores, dim3(512),   dim3(512), 0, stream, xh, xl, invn, best);
    hipLaunchKernelGGL(k_topk,   dim3(128),   dim3(256), 0, stream, best, wkey, member, dstmap);
    hipLaunchKernelGGL(k_merge2, dim3(16384), dim3(64),  0, stream, x, wkey, xh, xl);
    hipLaunchKernelGGL(k_out,    dim3(256),   dim3(512), 0, stream, xh, xl, Wh, Wl, bias, out);
    hipLaunchKernelGGL(k_fix,    dim3(16384), dim3(128), 0, stream, member, dstmap, out);
}

// Round 8
// 341.192 us; speedup vs baseline: 1.2538x; 1.2538x over previous
//
#include <hip/hip_runtime.h>
#include <stdint.h>

#define NB   8
#define TOK  4096
#define DIM  512
#define HALF 2048
#define RR   1024

typedef unsigned long long u64;
typedef unsigned int u32;
typedef _Float16 f16;
typedef f16 f16x4 __attribute__((ext_vector_type(4)));
typedef f16 f16x8 __attribute__((ext_vector_type(8)));
typedef float f32x4 __attribute__((ext_vector_type(4)));

#define AS1 __attribute__((address_space(1)))
#define AS3 __attribute__((address_space(3)))
#define GLL16(GP, LP) __builtin_amdgcn_global_load_lds((const AS1 u32*)(GP), (AS3 u32*)(LP), 16, 0, 0)

__device__ __forceinline__ u32 mono_f32(float f) {
    u32 u = __float_as_uint(f);
    return (u & 0x80000000u) ? ~u : (u | 0x80000000u);
}
__device__ __forceinline__ u64 umax64(u64 a, u64 b) { return a > b ? a : b; }

// ---------------- K0: init ----------------
__global__ void k_init(u64* __restrict__ best, u64* __restrict__ wkey) {
    int i = blockIdx.x * 256 + threadIdx.x;
    if (i < NB * HALF) { best[i] = 0ull; wkey[i] = ~0ull; }
}

// ---------------- fused split + norms ----------------
__global__ void k_prep(const float* __restrict__ x, f16* __restrict__ xh, f16* __restrict__ xl,
                       float* __restrict__ invn) {
    int row  = blockIdx.x * 4 + (threadIdx.x >> 6);
    int lane = threadIdx.x & 63;
    const float* p = x + (size_t)row * DIM + 4 * lane;
    float4 v0 = *(const float4*)p;
    float4 v1 = *(const float4*)(p + 256);
    float va[8] = {v0.x, v0.y, v0.z, v0.w, v1.x, v1.y, v1.z, v1.w};
    f16x4 h0, h1, l0, l1;
#pragma unroll
    for (int e = 0; e < 4; ++e) {
        f16 hh = (f16)va[e];     h0[e] = hh;  l0[e] = (f16)(va[e] - (float)hh);
        f16 hh1 = (f16)va[e+4];  h1[e] = hh1; l1[e] = (f16)(va[e+4] - (float)hh1);
    }
    size_t off = (size_t)row * DIM + 4 * lane;
    *(f16x4*)(xh + off)       = h0;
    *(f16x4*)(xh + off + 256) = h1;
    *(f16x4*)(xl + off)       = l0;
    *(f16x4*)(xl + off + 256) = l1;
    float ss = va[0]*va[0] + va[1]*va[1] + va[2]*va[2] + va[3]*va[3]
             + va[4]*va[4] + va[5]*va[5] + va[6]*va[6] + va[7]*va[7];
#pragma unroll
    for (int m = 32; m; m >>= 1) ss += __shfl_xor(ss, m, 64);
    if (lane == 0) invn[row] = 1.0f / fmaxf(sqrtf(ss), 1e-12f);
}

// ---------------- split + transpose W ----------------
__global__ void k_wsplit(const float* __restrict__ W, f16* __restrict__ Wh, f16* __restrict__ Wl) {
    __shared__ float tile[64][65];
    int k0 = (blockIdx.x >> 3) * 64, n0 = (blockIdx.x & 7) * 64;
    int t = threadIdx.x;
#pragma unroll
    for (int i = 0; i < 16; ++i) {
        int idx = t + 256 * i;
        int r = idx >> 6, c = idx & 63;
        tile[r][c] = W[(size_t)(k0 + r) * DIM + n0 + c];
    }
    __syncthreads();
#pragma unroll
    for (int i = 0; i < 16; ++i) {
        int idx = t + 256 * i;
        int n = idx >> 6, k = idx & 63;
        float v = tile[k][n];
        f16 h = (f16)v;
        Wh[(size_t)(n0 + n) * DIM + k0 + k] = h;
        Wl[(size_t)(n0 + n) * DIM + k0 + k] = (f16)(v - (float)h);
    }
}

// ======== fused-thirds 128x128 GEMM core ========
// LDS: 4 quarters [128][64] f16 (Ah, Al, Bh, Bl) = 64 KB, each XOR-swizzled
// (granule g: row m=g>>3, slot s=g&7 holds chunk s^(m&7); read chunk ch at slot ch^(m&7)).
// Per physical K-chunk of 64: stage all 4 quarters (16 GLL16/thread), then per acc:
//   acc += ah*bh + al*bh + ah*bl  (3 MFMA sharing fragment loads -> 96 MFMA : 32 ds_read/wave).

// ---------------- scores GEMM + fused row argmax ----------------
__launch_bounds__(256, 2)
__global__ void k_scores(const f16* __restrict__ xh, const f16* __restrict__ xl,
                         const float* __restrict__ invn, u64* __restrict__ best) {
    __shared__ __align__(16) f16 L[4][128][64];   // Ah | Al | Bh | Bl
    int bx = blockIdx.x;
    int b = bx >> 8, sb = (bx >> 4) & 15, tb = bx & 15;
    int tid = threadIdx.x, lane = tid & 63, w = tid >> 6, wr = w >> 1, wc = w & 1;
    int cc = lane >> 4, rm = lane & 15, rm7 = rm & 7;
    f16* L0 = &L[0][0][0];

    f32x4 acc[4][4];
#pragma unroll
    for (int i = 0; i < 4; ++i)
#pragma unroll
        for (int j = 0; j < 4; ++j) acc[i][j] = (f32x4){0.f, 0.f, 0.f, 0.f};

    size_t rowA[4], rowB[4];
#pragma unroll
    for (int r = 0; r < 4; ++r) {
        int g = tid + 256 * r;
        int m = g >> 3;
        int chunk = (g & 7) ^ (m & 7);
        rowA[r] = ((size_t)b * TOK + 2 * (sb * 128 + m) + 1) * DIM + 8 * chunk;
        rowB[r] = ((size_t)b * TOK + 2 * (tb * 128 + m)    ) * DIM + 8 * chunk;
    }

    for (int ks = 0; ks < 8; ++ks) {
        int col0 = ks << 6;
#pragma unroll
        for (int r = 0; r < 4; ++r) {
            size_t d = (size_t)(256 * r + 64 * w) * 8;
            GLL16(xh + rowA[r] + col0, L0 + d);           // Ah
            GLL16(xl + rowA[r] + col0, L0 + 8192 + d);    // Al
            GLL16(xh + rowB[r] + col0, L0 + 16384 + d);   // Bh
            GLL16(xl + rowB[r] + col0, L0 + 24576 + d);   // Bl
        }
        __syncthreads();   // drains vmcnt(0): tiles ready
        const f16* Ah = L0 + (wr * 64 + rm) * 64;
        const f16* Bh = L0 + 16384 + (wc * 64 + rm) * 64;
#pragma unroll
        for (int kk = 0; kk < 2; ++kk) {
            int ex = 8 * ((kk * 4 + cc) ^ rm7);
            f16x8 ah[4], al[4], bh[4], bl[4];
#pragma unroll
            for (int f = 0; f < 4; ++f) {
                ah[f] = *(const f16x8*)(Ah + f * 1024 + ex);
                al[f] = *(const f16x8*)(Ah + 8192 + f * 1024 + ex);
                bh[f] = *(const f16x8*)(Bh + f * 1024 + ex);
                bl[f] = *(const f16x8*)(Bh + 8192 + f * 1024 + ex);
            }
#pragma unroll
            for (int i = 0; i < 4; ++i)
#pragma unroll
                for (int j = 0; j < 4; ++j) {
                    acc[i][j] = __builtin_amdgcn_mfma_f32_16x16x32_f16(ah[i], bh[j], acc[i][j], 0, 0, 0);
                    acc[i][j] = __builtin_amdgcn_mfma_f32_16x16x32_f16(al[i], bh[j], acc[i][j], 0, 0, 0);
                    acc[i][j] = __builtin_amdgcn_mfma_f32_16x16x32_f16(ah[i], bl[j], acc[i][j], 0, 0, 0);
                }
        }
        __syncthreads();   // protect LDS before restage
    }

    float invd[4];
#pragma unroll
    for (int j = 0; j < 4; ++j) {
        int t = tb * 128 + wc * 64 + j * 16 + rm;
        invd[j] = invn[(size_t)b * TOK + 2 * t];
    }
#pragma unroll
    for (int i = 0; i < 4; ++i) {
#pragma unroll
        for (int r = 0; r < 4; ++r) {
            int s = sb * 128 + wr * 64 + i * 16 + cc * 4 + r;   // C row = (lane>>4)*4 + reg
            float invs = invn[(size_t)b * TOK + 2 * s + 1];
            u64 key = 0;
#pragma unroll
            for (int j = 0; j < 4; ++j) {
                int t = tb * 128 + wc * 64 + j * 16 + rm;       // C col = lane&15
                float sc = acc[i][j][r] * invs * invd[j];
                u64 k = ((u64)mono_f32(sc) << 32) | (u32)(2047 - t);
                key = umax64(key, k);
            }
#pragma unroll
            for (int m = 1; m < 16; m <<= 1) {
                u32 lo = (u32)key, hi = (u32)(key >> 32);
                lo = __shfl_xor(lo, m, 64);
                hi = __shfl_xor(hi, m, 64);
                key = umax64(key, ((u64)hi << 32) | lo);
            }
            if (rm == 0) atomicMax(&best[b * HALF + s], key);
        }
    }
}

// ---------------- top-k + duplicate-dst winner ----------------
__global__ void k_topk(const u64* __restrict__ best, u64* __restrict__ wkey,
                       u32* __restrict__ member, u32* __restrict__ dstmap) {
    __shared__ u32 smono[HALF];
    int b = blockIdx.x >> 4, sc = blockIdx.x & 15;
    int tid = threadIdx.x;
#pragma unroll
    for (int r = 0; r < 8; ++r) { int s = r * 256 + tid; smono[s] = (u32)(best[b * HALF + s] >> 32); }
    __syncthreads();
    int s = sc * 128 + (tid >> 1);
    u32 ms = smono[s];
    int t0 = (tid & 1) * 1024;
    int cnt = 0;
    for (int t = t0; t < t0 + 1024; ++t) {
        u32 mt = smono[t];
        cnt += ((mt > ms) || (mt == ms && t < s)) ? 1 : 0;
    }
    int oth = __shfl_xor(cnt, 1, 64);
    if ((tid & 1) == 0) {
        int rank = cnt + oth;
        u64 k = best[b * HALF + s];
        u32 d = 2047u - (u32)(k & 0xffffffffu);
        dstmap[b * HALF + s] = d;
        u32 mem = (rank < RR) ? 1u : 0u;
        member[b * HALF + s] = mem;
        if (mem) {
            u64 key = (k & 0xffffffff00000000ull) | (u32)(2047 - s);
            atomicMin(&wkey[b * HALF + d], key);   // last-wins: lowest score, then largest s
        }
    }
}

// ---------------- merged dst rows -> split((dst+src)/2) ----------------
__global__ void k_merge2(const float* __restrict__ x, const u64* __restrict__ wkey,
                         f16* __restrict__ xh, f16* __restrict__ xl) {
    int idx = blockIdx.x;
    int b = idx >> 11, d = idx & (HALF - 1);
    u64 wk = wkey[b * HALF + d];
    if (wk == ~0ull) return;
    int s = 2047 - (int)(wk & 0xffffffffu);
    const float* xd = x + ((size_t)b * TOK + 2 * d) * DIM;
    const float* xs = x + ((size_t)b * TOK + 2 * s + 1) * DIM;
    int l0 = threadIdx.x * 8;
    f16x8 h, l;
#pragma unroll
    for (int e = 0; e < 8; ++e) {
        float v = (xd[l0 + e] + xs[l0 + e]) * 0.5f;
        f16 hh = (f16)v;
        h[e] = hh;
        l[e] = (f16)(v - (float)hh);
    }
    size_t off = ((size_t)b * TOK + 2 * d) * DIM + l0;
    *(f16x8*)(xh + off) = h;
    *(f16x8*)(xl + off) = l;
}

// ---------------- y = x_merged @ W + b ----------------
__launch_bounds__(256, 2)
__global__ void k_out(const f16* __restrict__ xh, const f16* __restrict__ xl,
                      const f16* __restrict__ Wh, const f16* __restrict__ Wl,
                      const float* __restrict__ bias, float* __restrict__ out) {
    __shared__ __align__(16) f16 L[4][128][64];   // Ah | Al | Bh | Bl
    int bx = blockIdx.x;
    int im = bx >> 2, in = bx & 3;
    int tid = threadIdx.x, lane = tid & 63, w = tid >> 6, wr = w >> 1, wc = w & 1;
    int cc = lane >> 4, rm = lane & 15, rm7 = rm & 7;
    f16* L0 = &L[0][0][0];

    f32x4 acc[4][4];
#pragma unroll
    for (int i = 0; i < 4; ++i)
#pragma unroll
        for (int j = 0; j < 4; ++j) acc[i][j] = (f32x4){0.f, 0.f, 0.f, 0.f};

    size_t rowA[4], rowB[4];
#pragma unroll
    for (int r = 0; r < 4; ++r) {
        int g = tid + 256 * r;
        int m = g >> 3;
        int chunk = (g & 7) ^ (m & 7);
        rowA[r] = (size_t)(im * 128 + m) * DIM + 8 * chunk;
        rowB[r] = (size_t)(in * 128 + m) * DIM + 8 * chunk;
    }

    for (int ks = 0; ks < 8; ++ks) {
        int col0 = ks << 6;
#pragma unroll
        for (int r = 0; r < 4; ++r) {
            size_t d = (size_t)(256 * r + 64 * w) * 8;
            GLL16(xh + rowA[r] + col0, L0 + d);           // Ah
            GLL16(xl + rowA[r] + col0, L0 + 8192 + d);    // Al
            GLL16(Wh + rowB[r] + col0, L0 + 16384 + d);   // Bh
            GLL16(Wl + rowB[r] + col0, L0 + 24576 + d);   // Bl
        }
        __syncthreads();
        const f16* Ah = L0 + (wr * 64 + rm) * 64;
        const f16* Bh = L0 + 16384 + (wc * 64 + rm) * 64;
#pragma unroll
        for (int kk = 0; kk < 2; ++kk) {
            int ex = 8 * ((kk * 4 + cc) ^ rm7);
            f16x8 ah[4], al[4], bh[4], bl[4];
#pragma unroll
            for (int f = 0; f < 4; ++f) {
                ah[f] = *(const f16x8*)(Ah + f * 1024 + ex);
                al[f] = *(const f16x8*)(Ah + 8192 + f * 1024 + ex);
                bh[f] = *(const f16x8*)(Bh + f * 1024 + ex);
                bl[f] = *(const f16x8*)(Bh + 8192 + f * 1024 + ex);
            }
#pragma unroll
            for (int i = 0; i < 4; ++i)
#pragma unroll
                for (int j = 0; j < 4; ++j) {
                    acc[i][j] = __builtin_amdgcn_mfma_f32_16x16x32_f16(ah[i], bh[j], acc[i][j], 0, 0, 0);
                    acc[i][j] = __builtin_amdgcn_mfma_f32_16x16x32_f16(al[i], bh[j], acc[i][j], 0, 0, 0);
                    acc[i][j] = __builtin_amdgcn_mfma_f32_16x16x32_f16(ah[i], bl[j], acc[i][j], 0, 0, 0);
                }
        }
        __syncthreads();
    }

    float bj[4];
#pragma unroll
    for (int j = 0; j < 4; ++j) bj[j] = bias[in * 128 + wc * 64 + j * 16 + rm];
#pragma unroll
    for (int i = 0; i < 4; ++i) {
#pragma unroll
        for (int r = 0; r < 4; ++r) {
            int gm = im * 128 + wr * 64 + i * 16 + cc * 4 + r;
#pragma unroll
            for (int j = 0; j < 4; ++j) {
                int n = in * 128 + wc * 64 + j * 16 + rm;
                out[(size_t)gm * DIM + n] = acc[i][j][r] + bj[j];
            }
        }
    }
}

// ---------------- merged src rows copy dst hidden row ----------------
__global__ void k_fix(const u32* __restrict__ member, const u32* __restrict__ dstmap,
                      float* __restrict__ out) {
    int idx = blockIdx.x;
    if (!member[idx]) return;
    int b = idx >> 11, s = idx & (HALF - 1);
    const float* sp = out + ((size_t)b * TOK + 2 * (size_t)dstmap[idx]) * DIM;
    float*       dp = out + ((size_t)b * TOK + 2 * (size_t)s + 1) * DIM;
    int l = threadIdx.x;
    *(float4*)(dp + 4 * l) = *(const float4*)(sp + 4 * l);
}

extern "C" void kernel_launch(void* const* d_in, const int* in_sizes, int n_in,
                              void* d_out, int out_size, void* d_ws, size_t ws_size,
                              hipStream_t stream) {
    const float* x    = (const float*)d_in[0];
    const float* W    = (const float*)d_in[1];
    const float* bias = (const float*)d_in[2];
    float* out = (float*)d_out;

    char* ws = (char*)d_ws;
    f16*   xh     = (f16*)(ws);                               // 32 MB
    f16*   xl     = (f16*)(ws + (32u << 20));                 // 32 MB
    f16*   Wh     = (f16*)(ws + (64u << 20));                 // 512 KB
    f16*   Wl     = (f16*)(ws + (64u << 20) + (512u << 10));  // 512 KB
    float* invn   = (float*)(ws + (65u << 20));               // 128 KB
    u64*   best   = (u64*)(ws + (65u << 20) + (128u << 10));  // 128 KB
    u64*   wkey   = (u64*)(ws + (65u << 20) + (256u << 10));  // 128 KB
    u32*   dstmap = (u32*)(ws + (65u << 20) + (384u << 10));  //  64 KB
    u32*   member = (u32*)(ws + (65u << 20) + (448u << 10));  //  64 KB

    hipLaunchKernelGGL(k_init,   dim3(64),    dim3(256), 0, stream, best, wkey);
    hipLaunchKernelGGL(k_prep,   dim3(8192),  dim3(256), 0, stream, x, xh, xl, invn);
    hipLaunchKernelGGL(k_wsplit, dim3(64),    dim3(256), 0, stream, W, Wh, Wl);
    hipLaunchKernelGGL(k_scores, dim3(2048),  dim3(256), 0, stream, xh, xl, invn, best);
    hipLaunchKernelGGL(k_topk,   dim3(128),   dim3(256), 0, stream, best, wkey, member, dstmap);
    hipLaunchKernelGGL(k_merge2, dim3(16384), dim3(64),  0, stream, x, wkey, xh, xl);
    hipLaunchKernelGGL(k_out,    dim3(1024),  dim3(256), 0, stream, xh, xl, Wh, Wl, bias, out);
    hipLaunchKernelGGL(k_fix,    dim3(16384), dim3(128), 0, stream, member, dstmap, out);
}